// Round 2
// 646.586 us; speedup vs baseline: 1.1644x; 1.1644x over previous
//
#include <hip/hip_runtime.h>

// Problem constants (from reference setup_inputs)
constexpr int BB    = 2;
constexpr int NN    = 50000;
constexpr int CC    = 64;     // channels == wave size
constexpr int MM    = 50000;
constexpr int KK    = 16;     // neighbors
constexpr int HH    = 8;      // heads -> C/H = 8 channels per head
constexpr int CMID  = 16;

// Native clang vector type: __builtin_nontemporal_* rejects HIP_vector_type.
typedef float f32x4 __attribute__((ext_vector_type(4)));

// One wave (64 lanes) per (b,m). Lane = channel c. Each lane accumulates
// out[c, 0..15] in registers. out[b,m,c*CMID+w].
//
// v2: latency-bound fix. Prefetch all 16 guid values + all 16 gathered feat
// rows into registers (33 independent loads in flight), stage the 1 KiB wnet
// tile through LDS (1 global dwordx4/lane instead of 64 wave-uniform loads),
// and use nontemporal hints on the streamed guid/wnet/out so they stop
// evicting the 25.6 MB feat table from L2/L3.
__global__ __launch_bounds__(256) void pcf_kernel(
    const float* __restrict__ feat,   // [B,N,C]
    const int*   __restrict__ inds,   // [B,M,K]
    const float* __restrict__ guid,   // [B,M,K,H]
    const float* __restrict__ wnet,   // [B,M,K,CMID]
    float*       __restrict__ out)    // [B,M,C*CMID]
{
    const int wib  = threadIdx.x >> 6;                       // wave-in-block 0..3
    const int wid  = blockIdx.x * (blockDim.x >> 6) + wib;
    const int lane = threadIdx.x & 63;
    if (wid >= BB * MM) return;

    const int b = wid / MM;

    const float*  fbase = feat + (size_t)b * NN * CC;
    const int*    idx   = inds + (size_t)wid * KK;
    const float*  gd    = guid + (size_t)wid * KK * HH;
    const f32x4*  wn4   = (const f32x4*)(wnet + (size_t)wid * KK * CMID);

    // Per-wave wnet tile staged in LDS: K*CMID = 256 floats = 64 float4 = 1 KiB.
    // Each lane loads exactly one float4 -> whole tile in ONE vector load.
    // No __syncthreads needed: each wave reads only its own slice.
    __shared__ f32x4 swn[4][KK * 4];
    swn[wib][lane] = __builtin_nontemporal_load(&wn4[lane]);

    const int h = lane >> 3;  // head for this channel

    // Neighbor indices: lane i holds idx[i&15] (one broadcast txn).
    int myidx = idx[lane & (KK - 1)];

    // ---- Prefetch phase: issue all independent loads back-to-back ----

    // Guidance: 16 independent scalar loads (8 distinct dwords/wave each).
    float g[KK];
#pragma unroll
    for (int k = 0; k < KK; ++k)
        g[k] = __builtin_nontemporal_load(&gd[k * HH + h]);

    // Gathered feature rows: 16 independent coalesced 256B loads.
    // (feat is only 25.6 MB -> L2/L3 resident; keep these cacheable.)
    float f[KK];
#pragma unroll
    for (int k = 0; k < KK; ++k) {
        const int id = __shfl(myidx, k);                  // wave-uniform index
        f[k] = fbase[(size_t)id * CC + lane];
    }

    // ---- Compute phase: FMAs against LDS-broadcast wnet ----

    float acc[CMID];
#pragma unroll
    for (int i = 0; i < CMID; ++i) acc[i] = 0.f;

#pragma unroll
    for (int k = 0; k < KK; ++k) {
        const float fg = f[k] * g[k];

        const f32x4 w0 = swn[wib][k * 4 + 0];   // same-address broadcast,
        const f32x4 w1 = swn[wib][k * 4 + 1];   // conflict-free ds_read_b128
        const f32x4 w2 = swn[wib][k * 4 + 2];
        const f32x4 w3 = swn[wib][k * 4 + 3];

        acc[0]  += fg * w0.x;  acc[1]  += fg * w0.y;
        acc[2]  += fg * w0.z;  acc[3]  += fg * w0.w;
        acc[4]  += fg * w1.x;  acc[5]  += fg * w1.y;
        acc[6]  += fg * w1.z;  acc[7]  += fg * w1.w;
        acc[8]  += fg * w2.x;  acc[9]  += fg * w2.y;
        acc[10] += fg * w2.z;  acc[11] += fg * w2.w;
        acc[12] += fg * w3.x;  acc[13] += fg * w3.y;
        acc[14] += fg * w3.z;  acc[15] += fg * w3.w;
    }

    // Store: lane c owns out[wid, c*16 .. c*16+15] -> 4 contiguous float4.
    // Pure streaming output (400 MB), never re-read -> nontemporal.
    f32x4* o = (f32x4*)(out + (size_t)wid * (CC * CMID) + (size_t)lane * CMID);
    f32x4 o0 = {acc[0],  acc[1],  acc[2],  acc[3]};
    f32x4 o1 = {acc[4],  acc[5],  acc[6],  acc[7]};
    f32x4 o2 = {acc[8],  acc[9],  acc[10], acc[11]};
    f32x4 o3 = {acc[12], acc[13], acc[14], acc[15]};
    __builtin_nontemporal_store(o0, o + 0);
    __builtin_nontemporal_store(o1, o + 1);
    __builtin_nontemporal_store(o2, o + 2);
    __builtin_nontemporal_store(o3, o + 3);
}

extern "C" void kernel_launch(void* const* d_in, const int* in_sizes, int n_in,
                              void* d_out, int out_size, void* d_ws, size_t ws_size,
                              hipStream_t stream) {
    const float* feat = (const float*)d_in[0];   // [B,N,C] fp32
    const int*   inds = (const int*)d_in[1];     // [B,M,K] int
    const float* guid = (const float*)d_in[2];   // [B,M,K,H] fp32
    const float* wnet = (const float*)d_in[3];   // [B,M,K,CMID] fp32
    float*       out  = (float*)d_out;           // [B,M,C*CMID] fp32

    const int total_waves = BB * MM;             // 100000
    const int waves_per_block = 4;               // 256 threads
    const int blocks = (total_waves + waves_per_block - 1) / waves_per_block;

    pcf_kernel<<<blocks, 256, 0, stream>>>(feat, inds, guid, wnet, out);
}

// Round 3
// 591.357 us; speedup vs baseline: 1.2731x; 1.0934x over previous
//
#include <hip/hip_runtime.h>

// Problem constants (from reference setup_inputs)
constexpr int BB    = 2;
constexpr int NN    = 50000;
constexpr int CC    = 64;     // channels == wave size
constexpr int MM    = 50000;
constexpr int KK    = 16;     // neighbors
constexpr int HH    = 8;      // heads -> C/H = 8 channels per head
constexpr int CMID  = 16;

// Native clang vector type: __builtin_nontemporal_* rejects HIP_vector_type.
typedef float f32x4 __attribute__((ext_vector_type(4)));

// One wave (64 lanes) per (b,m). Lane = channel c. Each lane accumulates
// out[c, 0..15] in registers. out[b,m,c*CMID+w].
//
// v3: R2 post-mortem showed VGPR=44 -> the register allocator SANK the
// prefetched gathers back into the compute loop (acc+f+g alone need ~48
// regs), so MLP was ~5 not 33. Fix: keep-alive asm pins all 32 prefetch
// loads in flight (VGPR ~75, still 6 waves/SIMD). Also: WRITE_SIZE showed
// +45% inflation with nontemporal stores -> revert stores to cached
// full-line stores; keep NT only on the streamed *loads* (guid/wnet).
__global__ __launch_bounds__(256) void pcf_kernel(
    const float* __restrict__ feat,   // [B,N,C]
    const int*   __restrict__ inds,   // [B,M,K]
    const float* __restrict__ guid,   // [B,M,K,H]
    const float* __restrict__ wnet,   // [B,M,K,CMID]
    float*       __restrict__ out)    // [B,M,C*CMID]
{
    const int wib  = threadIdx.x >> 6;                       // wave-in-block 0..3
    const int wid  = blockIdx.x * (blockDim.x >> 6) + wib;
    const int lane = threadIdx.x & 63;
    if (wid >= BB * MM) return;

    const int b = wid / MM;

    const float*  fbase = feat + (size_t)b * NN * CC;
    const int*    idx   = inds + (size_t)wid * KK;
    const float*  gd    = guid + (size_t)wid * KK * HH;
    const f32x4*  wn4   = (const f32x4*)(wnet + (size_t)wid * KK * CMID);

    // Per-wave wnet tile staged in LDS: K*CMID = 256 floats = 64 float4 = 1 KiB.
    // Each lane loads exactly one float4 -> whole tile in ONE vector load.
    // No __syncthreads needed: each wave reads only its own slice.
    __shared__ f32x4 swn[4][KK * 4];
    swn[wib][lane] = __builtin_nontemporal_load(&wn4[lane]);

    const int h = lane >> 3;  // head for this channel

    // Neighbor indices: lane i holds idx[i&15] (one broadcast txn).
    int myidx = idx[lane & (KK - 1)];

    // ---- Prefetch phase: issue all independent loads back-to-back ----

    // Guidance: 16 independent scalar loads (8 distinct dwords/wave each).
    float g[KK];
#pragma unroll
    for (int k = 0; k < KK; ++k)
        g[k] = __builtin_nontemporal_load(&gd[k * HH + h]);

    // Gathered feature rows: 16 independent coalesced 256B loads.
    float f[KK];
#pragma unroll
    for (int k = 0; k < KK; ++k) {
        const int id = __shfl(myidx, k);                  // wave-uniform index
        f[k] = fbase[(size_t)id * CC + lane];
    }

    // Keep-alive: force all 32 prefetched values to materialize in VGPRs
    // BEFORE the compute loop, so the scheduler cannot sink the loads back
    // into the loop to save registers (R2: VGPR=44 proved it did exactly
    // that). Costs ~32 VGPRs, buys ~32-deep memory-level parallelism.
#pragma unroll
    for (int k = 0; k < KK; ++k)
        asm volatile("" :: "v"(f[k]), "v"(g[k]));

    // ---- Compute phase: FMAs against LDS-broadcast wnet ----

    float acc[CMID];
#pragma unroll
    for (int i = 0; i < CMID; ++i) acc[i] = 0.f;

#pragma unroll
    for (int k = 0; k < KK; ++k) {
        const float fg = f[k] * g[k];

        const f32x4 w0 = swn[wib][k * 4 + 0];   // same-address broadcast,
        const f32x4 w1 = swn[wib][k * 4 + 1];   // conflict-free ds_read_b128
        const f32x4 w2 = swn[wib][k * 4 + 2];
        const f32x4 w3 = swn[wib][k * 4 + 3];

        acc[0]  += fg * w0.x;  acc[1]  += fg * w0.y;
        acc[2]  += fg * w0.z;  acc[3]  += fg * w0.w;
        acc[4]  += fg * w1.x;  acc[5]  += fg * w1.y;
        acc[6]  += fg * w1.z;  acc[7]  += fg * w1.w;
        acc[8]  += fg * w2.x;  acc[9]  += fg * w2.y;
        acc[10] += fg * w2.z;  acc[11] += fg * w2.w;
        acc[12] += fg * w3.x;  acc[13] += fg * w3.y;
        acc[14] += fg * w3.z;  acc[15] += fg * w3.w;
    }

    // Store: lane c owns out[wid, c*16 .. c*16+15] -> 4 contiguous float4.
    // Plain cached stores: NT stores inflated WRITE_SIZE 410->590 MB (R2).
    f32x4* o = (f32x4*)(out + (size_t)wid * (CC * CMID) + (size_t)lane * CMID);
    f32x4 o0 = {acc[0],  acc[1],  acc[2],  acc[3]};
    f32x4 o1 = {acc[4],  acc[5],  acc[6],  acc[7]};
    f32x4 o2 = {acc[8],  acc[9],  acc[10], acc[11]};
    f32x4 o3 = {acc[12], acc[13], acc[14], acc[15]};
    o[0] = o0;
    o[1] = o1;
    o[2] = o2;
    o[3] = o3;
}

extern "C" void kernel_launch(void* const* d_in, const int* in_sizes, int n_in,
                              void* d_out, int out_size, void* d_ws, size_t ws_size,
                              hipStream_t stream) {
    const float* feat = (const float*)d_in[0];   // [B,N,C] fp32
    const int*   inds = (const int*)d_in[1];     // [B,M,K] int
    const float* guid = (const float*)d_in[2];   // [B,M,K,H] fp32
    const float* wnet = (const float*)d_in[3];   // [B,M,K,CMID] fp32
    float*       out  = (float*)d_out;           // [B,M,C*CMID] fp32

    const int total_waves = BB * MM;             // 100000
    const int waves_per_block = 4;               // 256 threads
    const int blocks = (total_waves + waves_per_block - 1) / waves_per_block;

    pcf_kernel<<<blocks, 256, 0, stream>>>(feat, inds, guid, wnet, out);
}